// Round 1
// baseline (507.261 us; speedup 1.0000x reference)
//
#include <hip/hip_runtime.h>
#include <hip/hip_bf16.h>

#define D_MODEL 1024
#define L_SEQ   2048
#define BATCH   2
#define NROWS   (BATCH*L_SEQ)   // 4096
#define N_HEADS 16
#define HD      64
#define WIN     128             // half window

typedef __attribute__((ext_vector_type(8))) short short8;
typedef __attribute__((ext_vector_type(4))) float f32x4;
typedef __attribute__((ext_vector_type(4))) int   i32x4;
typedef __attribute__((ext_vector_type(4))) unsigned short u16x4;

__device__ __forceinline__ float bf2f(unsigned short u) {
  union { unsigned int i; float f; } c;
  c.i = ((unsigned int)u) << 16;
  return c.f;
}
__device__ __forceinline__ unsigned short f2bf(float f) {
  __hip_bfloat16 h = __float2bfloat16(f);
  return *reinterpret_cast<unsigned short*>(&h);
}

// ---------------- weight transpose + f32->bf16 ----------------
// W [K][N] f32  ->  Wt [N][K] bf16
__global__ __launch_bounds__(256) void wtrans_kernel(const float* __restrict__ W,
                                                     __hip_bfloat16* __restrict__ Wt,
                                                     int K, int N) {
  __shared__ float tile[32][33];
  int tx = threadIdx.x & 31, ty = threadIdx.x >> 5;   // 32 x 8
  int n0 = blockIdx.x * 32, k0 = blockIdx.y * 32;
#pragma unroll
  for (int i = 0; i < 4; ++i) {
    int k = k0 + ty + i * 8;
    tile[ty + i * 8][tx] = W[(size_t)k * N + n0 + tx];
  }
  __syncthreads();
#pragma unroll
  for (int i = 0; i < 4; ++i) {
    int n = n0 + ty + i * 8;
    Wt[(size_t)n * K + k0 + tx] = __float2bfloat16(tile[tx][ty + i * 8]);
  }
}

// ---------------- layernorm (f32 in -> bf16 out) ----------------
__global__ __launch_bounds__(256) void ln_kernel(const float* __restrict__ x,
                                                 const float* __restrict__ g,
                                                 const float* __restrict__ beta,
                                                 __hip_bfloat16* __restrict__ out) {
  int row = blockIdx.x;
  int t = threadIdx.x;
  const float4* xr = (const float4*)(x + (size_t)row * D_MODEL);
  float4 v = xr[t];
  float s  = v.x + v.y + v.z + v.w;
  float sq = v.x * v.x + v.y * v.y + v.z * v.z + v.w * v.w;
#pragma unroll
  for (int off = 32; off; off >>= 1) {
    s  += __shfl_xor(s, off);
    sq += __shfl_xor(sq, off);
  }
  __shared__ float red[8];
  int w = t >> 6;
  if ((t & 63) == 0) { red[w] = s; red[4 + w] = sq; }
  __syncthreads();
  s  = red[0] + red[1] + red[2] + red[3];
  sq = red[4] + red[5] + red[6] + red[7];
  float mean = s * (1.0f / 1024.0f);
  float var  = sq * (1.0f / 1024.0f) - mean * mean;
  float rs   = rsqrtf(var + 1e-5f);
  float4 gv = ((const float4*)g)[t];
  float4 bv = ((const float4*)beta)[t];
  u16x4 o;
  o.x = f2bf((v.x - mean) * rs * gv.x + bv.x);
  o.y = f2bf((v.y - mean) * rs * gv.y + bv.y);
  o.z = f2bf((v.z - mean) * rs * gv.z + bv.z);
  o.w = f2bf((v.w - mean) * rs * gv.w + bv.w);
  ((u16x4*)(out + (size_t)row * D_MODEL))[t] = o;
}

// ---------------- MFMA GEMM: out = epilogue(A @ Bt^T + bias [+resid]) ----------------
// A [M][K] bf16, Bt [N][K] bf16. 128x128 tile, BK=64, 4 waves (2x2), each wave 64x64.
// MODE 0: bias -> bf16 out ; MODE 1: gelu(bias+acc) -> bf16 out ; MODE 2: bias+acc+resid -> f32 out
template <int MODE>
__global__ __launch_bounds__(256) void gemm_kernel(const __hip_bfloat16* __restrict__ A,
                                                   const __hip_bfloat16* __restrict__ Bt,
                                                   const float* __restrict__ bias,
                                                   const float* __restrict__ resid,
                                                   void* __restrict__ outp,
                                                   int M, int N, int K) {
  (void)M;
  __shared__ char lsA[128 * 128];
  __shared__ char lsB[128 * 128];

  int tid  = threadIdx.x;
  int lane = tid & 63;
  int wave = tid >> 6;
  int wr = wave >> 1, wc = wave & 1;

  int m0 = blockIdx.y * 128;
  int n0 = blockIdx.x * 128;

  const char* Abase = (const char*)A;
  const char* Bbase = (const char*)Bt;
  size_t strideK = (size_t)K * 2;   // bytes per row
  int KT = K >> 6;

  int srow = tid >> 3;         // 0..31 (+32 per chunk)
  int skb  = (tid & 7) * 16;   // byte within 128B row

  f32x4 zero = {0.f, 0.f, 0.f, 0.f};
  f32x4 acc[4][4];
#pragma unroll
  for (int i = 0; i < 4; ++i)
#pragma unroll
    for (int j = 0; j < 4; ++j) acc[i][j] = zero;

  i32x4 ra[4], rb[4];
  // prologue: fetch tile 0
#pragma unroll
  for (int c = 0; c < 4; ++c) {
    int row = srow + c * 32;
    ra[c] = *(const i32x4*)(Abase + (size_t)(m0 + row) * strideK + skb);
    rb[c] = *(const i32x4*)(Bbase + (size_t)(n0 + row) * strideK + skb);
  }
#pragma unroll
  for (int c = 0; c < 4; ++c) {
    int row = srow + c * 32;
    int kb  = skb ^ ((row & 7) << 4);
    *(i32x4*)(lsA + row * 128 + kb) = ra[c];
    *(i32x4*)(lsB + row * 128 + kb) = rb[c];
  }
  __syncthreads();

  for (int kt = 0; kt < KT; ++kt) {
    if (kt + 1 < KT) {
#pragma unroll
      for (int c = 0; c < 4; ++c) {
        int row = srow + c * 32;
        ra[c] = *(const i32x4*)(Abase + (size_t)(m0 + row) * strideK + (size_t)(kt + 1) * 128 + skb);
        rb[c] = *(const i32x4*)(Bbase + (size_t)(n0 + row) * strideK + (size_t)(kt + 1) * 128 + skb);
      }
    }
#pragma unroll
    for (int ks = 0; ks < 2; ++ks) {
      short8 af[4], bfr[4];
#pragma unroll
      for (int mi = 0; mi < 4; ++mi) {
        int row = wr * 64 + mi * 16 + (lane & 15);
        int kb  = (ks * 64 + ((lane >> 4) << 4)) ^ ((row & 7) << 4);
        af[mi] = *(const short8*)(lsA + row * 128 + kb);
      }
#pragma unroll
      for (int ni = 0; ni < 4; ++ni) {
        int row = wc * 64 + ni * 16 + (lane & 15);
        int kb  = (ks * 64 + ((lane >> 4) << 4)) ^ ((row & 7) << 4);
        bfr[ni] = *(const short8*)(lsB + row * 128 + kb);
      }
#pragma unroll
      for (int mi = 0; mi < 4; ++mi)
#pragma unroll
        for (int ni = 0; ni < 4; ++ni)
          acc[mi][ni] = __builtin_amdgcn_mfma_f32_16x16x32_bf16(af[mi], bfr[ni], acc[mi][ni], 0, 0, 0);
    }
    __syncthreads();
    if (kt + 1 < KT) {
#pragma unroll
      for (int c = 0; c < 4; ++c) {
        int row = srow + c * 32;
        int kb  = skb ^ ((row & 7) << 4);
        *(i32x4*)(lsA + row * 128 + kb) = ra[c];
        *(i32x4*)(lsB + row * 128 + kb) = rb[c];
      }
    }
    __syncthreads();
  }

  // epilogue: D row = 4*(lane>>4)+r, col = lane&15  (verified layout)
  int colg = n0 + wc * 64;
  int rowg = m0 + wr * 64;
#pragma unroll
  for (int mi = 0; mi < 4; ++mi) {
#pragma unroll
    for (int ni = 0; ni < 4; ++ni) {
      int col = colg + ni * 16 + (lane & 15);
      float bs = bias[col];
#pragma unroll
      for (int r = 0; r < 4; ++r) {
        int row = rowg + mi * 16 + ((lane >> 4) << 2) + r;
        float v = acc[mi][ni][r] + bs;
        if (MODE == 1) v = 0.5f * v * (1.0f + erff(v * 0.70710678118654752f));
        if (MODE == 2) {
          ((float*)outp)[(size_t)row * N + col] = v + resid[(size_t)row * N + col];
        } else {
          ((__hip_bfloat16*)outp)[(size_t)row * N + col] = __float2bfloat16(v);
        }
      }
    }
  }
}

// ---------------- windowed attention ----------------
// qkv [4096][3072] bf16 (q | k | v, each [H=16][hd=64]); out attn [4096][1024] bf16
__global__ __launch_bounds__(256) void attn_kernel(const __hip_bfloat16* __restrict__ qkv,
                                                   __hip_bfloat16* __restrict__ attn_out) {
  __shared__ __hip_bfloat16 Ks[272][72];   // pad 72 -> conflict-free-ish
  __shared__ __hip_bfloat16 Qs[16][64];
  __shared__ float Ss[16][272];

  int bh = blockIdx.y;
  int b = bh >> 4, h = bh & 15;
  int q0 = blockIdx.x << 4;
  int jlo = max(0, q0 - WIN);
  int jhi = min(L_SEQ - 1, q0 + 15 + WIN);
  int count = jhi - jlo + 1;   // <= 272

  int t = threadIdx.x;
  const size_t rs3 = 3 * D_MODEL;

  if (t < 128) {
    int r = t >> 3, ch = t & 7;
    *(i32x4*)&Qs[r][ch * 8] =
        *(const i32x4*)&qkv[(size_t)(b * L_SEQ + q0 + r) * rs3 + h * 64 + ch * 8];
  }
  for (int id = t; id < count * 8; id += 256) {
    int j = id >> 3, ch = id & 7;
    *(i32x4*)&Ks[j][ch * 8] =
        *(const i32x4*)&qkv[(size_t)(b * L_SEQ + jlo + j) * rs3 + D_MODEL + h * 64 + ch * 8];
  }
  __syncthreads();

  // scores
  int r   = t >> 4;
  int l16 = t & 15;
  int iq  = q0 + r;
  for (int jj = l16; jj < count; jj += 16) {
    int jg = jlo + jj;
    float s = 0.f;
#pragma unroll
    for (int c = 0; c < 8; ++c) {
      short8 kv = *(const short8*)&Ks[jj][c * 8];
      short8 qv = *(const short8*)&Qs[r][c * 8];
#pragma unroll
      for (int e = 0; e < 8; ++e)
        s += bf2f((unsigned short)qv[e]) * bf2f((unsigned short)kv[e]);
    }
    s *= 0.125f;   // 1/sqrt(64)
    if (jg < iq - WIN || jg > iq + WIN) s = -1e30f;
    Ss[r][jj] = s;
  }
  __syncthreads();

  // softmax (16 lanes per row)
  float mx = -1e30f;
  for (int jj = l16; jj < count; jj += 16) mx = fmaxf(mx, Ss[r][jj]);
#pragma unroll
  for (int off = 8; off; off >>= 1) mx = fmaxf(mx, __shfl_xor(mx, off, 16));
  float sum = 0.f;
  for (int jj = l16; jj < count; jj += 16) {
    float p = __expf(Ss[r][jj] - mx);
    Ss[r][jj] = p;
    sum += p;
  }
#pragma unroll
  for (int off = 8; off; off >>= 1) sum += __shfl_xor(sum, off, 16);
  float inv = 1.f / sum;
  for (int jj = l16; jj < count; jj += 16) Ss[r][jj] *= inv;
  __syncthreads();

  // PV: d = t&63, wave rg handles rows rg*4 .. rg*4+3 ; V read from global (L2-resident)
  int d  = t & 63;
  int rg = t >> 6;
  const unsigned short* vcol = (const unsigned short*)qkv + 2 * D_MODEL + h * 64 + d;
  float a0 = 0.f, a1 = 0.f, a2 = 0.f, a3 = 0.f;
  int jj = 0;
  for (; jj + 4 <= count; jj += 4) {
    float v0 = bf2f(vcol[(size_t)(b * L_SEQ + jlo + jj + 0) * rs3]);
    float v1 = bf2f(vcol[(size_t)(b * L_SEQ + jlo + jj + 1) * rs3]);
    float v2 = bf2f(vcol[(size_t)(b * L_SEQ + jlo + jj + 2) * rs3]);
    float v3 = bf2f(vcol[(size_t)(b * L_SEQ + jlo + jj + 3) * rs3]);
    a0 += Ss[rg * 4 + 0][jj] * v0 + Ss[rg * 4 + 0][jj + 1] * v1 + Ss[rg * 4 + 0][jj + 2] * v2 + Ss[rg * 4 + 0][jj + 3] * v3;
    a1 += Ss[rg * 4 + 1][jj] * v0 + Ss[rg * 4 + 1][jj + 1] * v1 + Ss[rg * 4 + 1][jj + 2] * v2 + Ss[rg * 4 + 1][jj + 3] * v3;
    a2 += Ss[rg * 4 + 2][jj] * v0 + Ss[rg * 4 + 2][jj + 1] * v1 + Ss[rg * 4 + 2][jj + 2] * v2 + Ss[rg * 4 + 2][jj + 3] * v3;
    a3 += Ss[rg * 4 + 3][jj] * v0 + Ss[rg * 4 + 3][jj + 1] * v1 + Ss[rg * 4 + 3][jj + 2] * v2 + Ss[rg * 4 + 3][jj + 3] * v3;
  }
  for (; jj < count; ++jj) {
    float v = bf2f(vcol[(size_t)(b * L_SEQ + jlo + jj) * rs3]);
    a0 += Ss[rg * 4 + 0][jj] * v;
    a1 += Ss[rg * 4 + 1][jj] * v;
    a2 += Ss[rg * 4 + 2][jj] * v;
    a3 += Ss[rg * 4 + 3][jj] * v;
  }
  size_t obase = (size_t)(b * L_SEQ + q0) * D_MODEL + h * 64 + d;
  attn_out[obase + (size_t)(rg * 4 + 0) * D_MODEL] = __float2bfloat16(a0);
  attn_out[obase + (size_t)(rg * 4 + 1) * D_MODEL] = __float2bfloat16(a1);
  attn_out[obase + (size_t)(rg * 4 + 2) * D_MODEL] = __float2bfloat16(a2);
  attn_out[obase + (size_t)(rg * 4 + 3) * D_MODEL] = __float2bfloat16(a3);
}

// ---------------- launcher ----------------
extern "C" void kernel_launch(void* const* d_in, const int* in_sizes, int n_in,
                              void* d_out, int out_size, void* d_ws, size_t ws_size,
                              hipStream_t stream) {
  const float* x      = (const float*)d_in[0];
  const float* qkv_w  = (const float*)d_in[1];
  const float* qkv_b  = (const float*)d_in[2];
  const float* out_w  = (const float*)d_in[3];
  const float* out_b  = (const float*)d_in[4];
  const float* ln1_g  = (const float*)d_in[5];
  const float* ln1_b  = (const float*)d_in[6];
  const float* ln2_g  = (const float*)d_in[7];
  const float* ln2_b  = (const float*)d_in[8];
  const float* ffn_w1 = (const float*)d_in[9];
  const float* ffn_b1 = (const float*)d_in[10];
  const float* ffn_w2 = (const float*)d_in[11];
  const float* ffn_b2 = (const float*)d_in[12];
  float* out = (float*)d_out;
  (void)in_sizes; (void)n_in; (void)out_size; (void)ws_size;

  char* ws = (char*)d_ws;
  size_t off = 0;
  auto alloc = [&](size_t bytes) {
    char* p = ws + off;
    off += (bytes + 255) & ~(size_t)255;
    return p;
  };
  __hip_bfloat16* hbuf    = (__hip_bfloat16*)alloc((size_t)NROWS * 1024 * 2);
  __hip_bfloat16* qkvbuf  = (__hip_bfloat16*)alloc((size_t)NROWS * 3072 * 2);
  __hip_bfloat16* attnbuf = (__hip_bfloat16*)alloc((size_t)NROWS * 1024 * 2);
  float*          x2buf   = (float*)alloc((size_t)NROWS * 1024 * 4);
  __hip_bfloat16* wqkvT   = (__hip_bfloat16*)alloc((size_t)3072 * 1024 * 2);
  __hip_bfloat16* woutT   = (__hip_bfloat16*)alloc((size_t)1024 * 1024 * 2);
  __hip_bfloat16* wf1T    = (__hip_bfloat16*)alloc((size_t)2048 * 1024 * 2);
  __hip_bfloat16* wf2T    = (__hip_bfloat16*)alloc((size_t)1024 * 2048 * 2);
  __hip_bfloat16* gbuf    = qkvbuf;   // reuse: qkv dead after attention

  dim3 blk(256);
  wtrans_kernel<<<dim3(3072 / 32, 1024 / 32), blk, 0, stream>>>(qkv_w, wqkvT, 1024, 3072);
  wtrans_kernel<<<dim3(1024 / 32, 1024 / 32), blk, 0, stream>>>(out_w, woutT, 1024, 1024);
  wtrans_kernel<<<dim3(2048 / 32, 1024 / 32), blk, 0, stream>>>(ffn_w1, wf1T, 1024, 2048);
  wtrans_kernel<<<dim3(1024 / 32, 2048 / 32), blk, 0, stream>>>(ffn_w2, wf2T, 2048, 1024);

  ln_kernel<<<NROWS, blk, 0, stream>>>(x, ln1_g, ln1_b, hbuf);
  gemm_kernel<0><<<dim3(3072 / 128, NROWS / 128), blk, 0, stream>>>(hbuf, wqkvT, qkv_b, nullptr, qkvbuf, NROWS, 3072, 1024);
  attn_kernel<<<dim3(L_SEQ / 16, BATCH * N_HEADS), blk, 0, stream>>>(qkvbuf, attnbuf);
  gemm_kernel<2><<<dim3(1024 / 128, NROWS / 128), blk, 0, stream>>>(attnbuf, woutT, out_b, x, x2buf, NROWS, 1024, 1024);
  ln_kernel<<<NROWS, blk, 0, stream>>>(x2buf, ln2_g, ln2_b, hbuf);
  gemm_kernel<1><<<dim3(2048 / 128, NROWS / 128), blk, 0, stream>>>(hbuf, wf1T, ffn_b1, nullptr, gbuf, NROWS, 2048, 1024);
  gemm_kernel<2><<<dim3(1024 / 128, NROWS / 128), blk, 0, stream>>>(gbuf, wf2T, ffn_b2, x2buf, out, NROWS, 1024, 2048);
}

// Round 2
// 259.508 us; speedup vs baseline: 1.9547x; 1.9547x over previous
//
#include <hip/hip_runtime.h>
#include <hip/hip_bf16.h>

#define D_MODEL 1024
#define L_SEQ   2048
#define BATCH   2
#define NROWS   (BATCH*L_SEQ)   // 4096
#define N_HEADS 16
#define HD      64
#define WIN     128             // half window

typedef __attribute__((ext_vector_type(8))) short short8;
typedef __attribute__((ext_vector_type(4))) float f32x4;
typedef __attribute__((ext_vector_type(4))) int   i32x4;
typedef __attribute__((ext_vector_type(4))) unsigned short u16x4;

__device__ __forceinline__ float bf2f(unsigned short u) {
  union { unsigned int i; float f; } c;
  c.i = ((unsigned int)u) << 16;
  return c.f;
}
__device__ __forceinline__ unsigned short f2bf(float f) {
  __hip_bfloat16 h = __float2bfloat16(f);
  return *reinterpret_cast<unsigned short*>(&h);
}

// ---------------- weight transpose + f32->bf16 ----------------
// W [K][N] f32  ->  Wt [N][K] bf16
__global__ __launch_bounds__(256) void wtrans_kernel(const float* __restrict__ W,
                                                     __hip_bfloat16* __restrict__ Wt,
                                                     int K, int N) {
  __shared__ float tile[32][33];
  int tx = threadIdx.x & 31, ty = threadIdx.x >> 5;   // 32 x 8
  int n0 = blockIdx.x * 32, k0 = blockIdx.y * 32;
#pragma unroll
  for (int i = 0; i < 4; ++i) {
    int k = k0 + ty + i * 8;
    tile[ty + i * 8][tx] = W[(size_t)k * N + n0 + tx];
  }
  __syncthreads();
#pragma unroll
  for (int i = 0; i < 4; ++i) {
    int n = n0 + ty + i * 8;
    Wt[(size_t)n * K + k0 + tx] = __float2bfloat16(tile[tx][ty + i * 8]);
  }
}

// ---------------- V transpose: qkv V part -> vT[bh][d][j] bf16 ----------------
__global__ __launch_bounds__(256) void vtrans_kernel(const __hip_bfloat16* __restrict__ qkv,
                                                     __hip_bfloat16* __restrict__ vT) {
  __shared__ unsigned short tile[64][72];
  int bh = blockIdx.y, b = bh >> 4, h = bh & 15;
  int j0 = blockIdx.x * 64;
  int t = threadIdx.x;
#pragma unroll
  for (int i = 0; i < 2; ++i) {
    int c = t + i * 256;            // 0..511
    int row = c >> 3, off = c & 7;  // row 0..63, 16B chunk
    *(i32x4*)&tile[row][off * 8] =
        *(const i32x4*)&qkv[(size_t)(b * L_SEQ + j0 + row) * 3072 + 2 * D_MODEL + h * 64 + off * 8];
  }
  __syncthreads();
#pragma unroll
  for (int i = 0; i < 2; ++i) {
    int c = t + i * 256;
    int d = c >> 3, off = c & 7;    // d 0..63, j chunk
    short8 o;
#pragma unroll
    for (int e = 0; e < 8; ++e) o[e] = (short)tile[off * 8 + e][d];
    *(short8*)&vT[((size_t)bh * 64 + d) * 2048 + j0 + off * 8] = o;
  }
}

// ---------------- layernorm (f32 in -> bf16 out) ----------------
__global__ __launch_bounds__(256) void ln_kernel(const float* __restrict__ x,
                                                 const float* __restrict__ g,
                                                 const float* __restrict__ beta,
                                                 __hip_bfloat16* __restrict__ out) {
  int row = blockIdx.x;
  int t = threadIdx.x;
  const float4* xr = (const float4*)(x + (size_t)row * D_MODEL);
  float4 v = xr[t];
  float s  = v.x + v.y + v.z + v.w;
  float sq = v.x * v.x + v.y * v.y + v.z * v.z + v.w * v.w;
#pragma unroll
  for (int off = 32; off; off >>= 1) {
    s  += __shfl_xor(s, off);
    sq += __shfl_xor(sq, off);
  }
  __shared__ float red[8];
  int w = t >> 6;
  if ((t & 63) == 0) { red[w] = s; red[4 + w] = sq; }
  __syncthreads();
  s  = red[0] + red[1] + red[2] + red[3];
  sq = red[4] + red[5] + red[6] + red[7];
  float mean = s * (1.0f / 1024.0f);
  float var  = sq * (1.0f / 1024.0f) - mean * mean;
  float rs   = rsqrtf(var + 1e-5f);
  float4 gv = ((const float4*)g)[t];
  float4 bv = ((const float4*)beta)[t];
  u16x4 o;
  o.x = f2bf((v.x - mean) * rs * gv.x + bv.x);
  o.y = f2bf((v.y - mean) * rs * gv.y + bv.y);
  o.z = f2bf((v.z - mean) * rs * gv.z + bv.z);
  o.w = f2bf((v.w - mean) * rs * gv.w + bv.w);
  ((u16x4*)(out + (size_t)row * D_MODEL))[t] = o;
}

// ---------------- MFMA GEMM: out = epilogue(A @ Bt^T + bias [+resid]) ----------------
template <int MODE>
__global__ __launch_bounds__(256) void gemm_kernel(const __hip_bfloat16* __restrict__ A,
                                                   const __hip_bfloat16* __restrict__ Bt,
                                                   const float* __restrict__ bias,
                                                   const float* __restrict__ resid,
                                                   void* __restrict__ outp,
                                                   int M, int N, int K) {
  (void)M;
  __shared__ char lsA[128 * 128];
  __shared__ char lsB[128 * 128];

  int tid  = threadIdx.x;
  int lane = tid & 63;
  int wave = tid >> 6;
  int wr = wave >> 1, wc = wave & 1;

  int m0 = blockIdx.y * 128;
  int n0 = blockIdx.x * 128;

  const char* Abase = (const char*)A;
  const char* Bbase = (const char*)Bt;
  size_t strideK = (size_t)K * 2;   // bytes per row
  int KT = K >> 6;

  int srow = tid >> 3;         // 0..31 (+32 per chunk)
  int skb  = (tid & 7) * 16;   // byte within 128B row

  f32x4 zero = {0.f, 0.f, 0.f, 0.f};
  f32x4 acc[4][4];
#pragma unroll
  for (int i = 0; i < 4; ++i)
#pragma unroll
    for (int j = 0; j < 4; ++j) acc[i][j] = zero;

  i32x4 ra[4], rb[4];
#pragma unroll
  for (int c = 0; c < 4; ++c) {
    int row = srow + c * 32;
    ra[c] = *(const i32x4*)(Abase + (size_t)(m0 + row) * strideK + skb);
    rb[c] = *(const i32x4*)(Bbase + (size_t)(n0 + row) * strideK + skb);
  }
#pragma unroll
  for (int c = 0; c < 4; ++c) {
    int row = srow + c * 32;
    int kb  = skb ^ ((row & 7) << 4);
    *(i32x4*)(lsA + row * 128 + kb) = ra[c];
    *(i32x4*)(lsB + row * 128 + kb) = rb[c];
  }
  __syncthreads();

  for (int kt = 0; kt < KT; ++kt) {
    if (kt + 1 < KT) {
#pragma unroll
      for (int c = 0; c < 4; ++c) {
        int row = srow + c * 32;
        ra[c] = *(const i32x4*)(Abase + (size_t)(m0 + row) * strideK + (size_t)(kt + 1) * 128 + skb);
        rb[c] = *(const i32x4*)(Bbase + (size_t)(n0 + row) * strideK + (size_t)(kt + 1) * 128 + skb);
      }
    }
#pragma unroll
    for (int ks = 0; ks < 2; ++ks) {
      short8 af[4], bfr[4];
#pragma unroll
      for (int mi = 0; mi < 4; ++mi) {
        int row = wr * 64 + mi * 16 + (lane & 15);
        int kb  = (ks * 64 + ((lane >> 4) << 4)) ^ ((row & 7) << 4);
        af[mi] = *(const short8*)(lsA + row * 128 + kb);
      }
#pragma unroll
      for (int ni = 0; ni < 4; ++ni) {
        int row = wc * 64 + ni * 16 + (lane & 15);
        int kb  = (ks * 64 + ((lane >> 4) << 4)) ^ ((row & 7) << 4);
        bfr[ni] = *(const short8*)(lsB + row * 128 + kb);
      }
#pragma unroll
      for (int mi = 0; mi < 4; ++mi)
#pragma unroll
        for (int ni = 0; ni < 4; ++ni)
          acc[mi][ni] = __builtin_amdgcn_mfma_f32_16x16x32_bf16(af[mi], bfr[ni], acc[mi][ni], 0, 0, 0);
    }
    __syncthreads();
    if (kt + 1 < KT) {
#pragma unroll
      for (int c = 0; c < 4; ++c) {
        int row = srow + c * 32;
        int kb  = skb ^ ((row & 7) << 4);
        *(i32x4*)(lsA + row * 128 + kb) = ra[c];
        *(i32x4*)(lsB + row * 128 + kb) = rb[c];
      }
    }
    __syncthreads();
  }

  int colg = n0 + wc * 64;
  int rowg = m0 + wr * 64;
#pragma unroll
  for (int mi = 0; mi < 4; ++mi) {
#pragma unroll
    for (int ni = 0; ni < 4; ++ni) {
      int col = colg + ni * 16 + (lane & 15);
      float bs = bias[col];
#pragma unroll
      for (int r = 0; r < 4; ++r) {
        int row = rowg + mi * 16 + ((lane >> 4) << 2) + r;
        float v = acc[mi][ni][r] + bs;
        if (MODE == 1) v = 0.5f * v * (1.0f + erff(v * 0.70710678118654752f));
        if (MODE == 2) {
          ((float*)outp)[(size_t)row * N + col] = v + resid[(size_t)row * N + col];
        } else {
          ((__hip_bfloat16*)outp)[(size_t)row * N + col] = __float2bfloat16(v);
        }
      }
    }
  }
}

// ---------------- MFMA windowed attention ----------------
// Block: 64 q-rows of one (b,h); 4 waves x 16 q-rows. 5 key chunks of 64 (=320 keys).
__global__ __launch_bounds__(256) void attn_mfma_kernel(const __hip_bfloat16* __restrict__ qkv,
                                                        const __hip_bfloat16* __restrict__ vT,
                                                        __hip_bfloat16* __restrict__ out) {
  __shared__ char Ks[2][8192];   // 64 keys x 128B (swizzled)
  __shared__ char Vs[2][8192];   // 64 d    x 128B of j (swizzled)
  __shared__ char Ps[4][2304];   // per-wave P chunk: 16 x 72 bf16

  const int t = threadIdx.x;
  const int lane = t & 63;
  const int wave = t >> 6;
  const int l15 = lane & 15;
  const int lg  = lane >> 4;
  const int bh = blockIdx.y, b = bh >> 4, h = bh & 15;
  const int q0 = blockIdx.x * 64;
  const int jlo = q0 - 128;

  // Q fragments (k = 0..31 and 32..63)
  short8 qf0, qf1;
  {
    int qrow = q0 + wave * 16 + l15;
    const char* qp = (const char*)qkv + 2 * ((size_t)(b * L_SEQ + qrow) * 3072 + h * 64 + 8 * lg);
    qf0 = *(const short8*)qp;
    qf1 = *(const short8*)(qp + 64);
  }

  const int srow = t >> 3;           // 0..31 (two rows per thread: srow, srow+32)
  const int soff = (t & 7) * 16;     // byte chunk in 128B row
  const int jel  = (t & 7) * 8;      // element offset (j)

  const char* kgbase = (const char*)qkv + 2 * ((size_t)b * L_SEQ * 3072 + D_MODEL + h * 64);
  const char* vgbase = (const char*)vT + 2 * ((size_t)bh * 64 * 2048);

  f32x4 sc[5][4];
#pragma unroll
  for (int c = 0; c < 5; ++c)
#pragma unroll
    for (int tt = 0; tt < 4; ++tt) sc[c][tt] = (f32x4){0.f, 0.f, 0.f, 0.f};

  // ---- pass 1: QK^T ----
  {
    i32x4 kr[2];
#pragma unroll
    for (int i = 0; i < 2; ++i) {
      int rr = srow + i * 32;
      int tok = jlo + rr; tok = tok < 0 ? 0 : (tok > 2047 ? 2047 : tok);
      kr[i] = *(const i32x4*)(kgbase + (size_t)tok * 6144 + soff);
    }
#pragma unroll
    for (int i = 0; i < 2; ++i) {
      int rr = srow + i * 32;
      *(i32x4*)(Ks[0] + rr * 128 + (soff ^ ((rr & 7) << 4))) = kr[i];
    }
  }
  __syncthreads();

#pragma unroll
  for (int c = 0; c < 5; ++c) {
    int cur = c & 1;
    i32x4 nk[2];
    if (c < 4) {
#pragma unroll
      for (int i = 0; i < 2; ++i) {
        int rr = srow + i * 32;
        int tok = jlo + (c + 1) * 64 + rr; tok = tok < 0 ? 0 : (tok > 2047 ? 2047 : tok);
        nk[i] = *(const i32x4*)(kgbase + (size_t)tok * 6144 + soff);
      }
    }
#pragma unroll
    for (int tt = 0; tt < 4; ++tt) {
      int row = tt * 16 + l15;
      short8 k0 = *(const short8*)(Ks[cur] + row * 128 + ((lg * 16) ^ ((row & 7) << 4)));
      short8 k1 = *(const short8*)(Ks[cur] + row * 128 + ((64 + lg * 16) ^ ((row & 7) << 4)));
      sc[c][tt] = __builtin_amdgcn_mfma_f32_16x16x32_bf16(qf0, k0, sc[c][tt], 0, 0, 0);
      sc[c][tt] = __builtin_amdgcn_mfma_f32_16x16x32_bf16(qf1, k1, sc[c][tt], 0, 0, 0);
    }
    if (c < 4) {
      __syncthreads();
#pragma unroll
      for (int i = 0; i < 2; ++i) {
        int rr = srow + i * 32;
        *(i32x4*)(Ks[cur ^ 1] + rr * 128 + (soff ^ ((rr & 7) << 4))) = nk[i];
      }
      __syncthreads();
    }
  }

  // ---- mask + softmax (exact, full scores in regs) ----
  const int iqb = q0 + wave * 16 + 4 * lg;
  const int kgb = jlo + l15;
#pragma unroll
  for (int c = 0; c < 5; ++c)
#pragma unroll
    for (int tt = 0; tt < 4; ++tt) {
      int kg = kgb + c * 64 + tt * 16;
#pragma unroll
      for (int r = 0; r < 4; ++r) {
        int iq = iqb + r;
        bool ok = (kg >= 0) && (kg < L_SEQ) && (kg >= iq - WIN) && (kg <= iq + WIN);
        sc[c][tt][r] = ok ? sc[c][tt][r] * 0.125f : -1e30f;
      }
    }
  float mx[4] = {-1e30f, -1e30f, -1e30f, -1e30f};
#pragma unroll
  for (int c = 0; c < 5; ++c)
#pragma unroll
    for (int tt = 0; tt < 4; ++tt)
#pragma unroll
      for (int r = 0; r < 4; ++r) mx[r] = fmaxf(mx[r], sc[c][tt][r]);
#pragma unroll
  for (int r = 0; r < 4; ++r)
#pragma unroll
    for (int off = 8; off; off >>= 1) mx[r] = fmaxf(mx[r], __shfl_xor(mx[r], off, 16));
  float sm[4] = {0.f, 0.f, 0.f, 0.f};
#pragma unroll
  for (int c = 0; c < 5; ++c)
#pragma unroll
    for (int tt = 0; tt < 4; ++tt)
#pragma unroll
      for (int r = 0; r < 4; ++r) {
        float p = __expf(sc[c][tt][r] - mx[r]);
        sc[c][tt][r] = p;
        sm[r] += p;
      }
#pragma unroll
  for (int r = 0; r < 4; ++r)
#pragma unroll
    for (int off = 8; off; off >>= 1) sm[r] += __shfl_xor(sm[r], off, 16);
  float inv[4];
#pragma unroll
  for (int r = 0; r < 4; ++r) inv[r] = 1.f / sm[r];
#pragma unroll
  for (int c = 0; c < 5; ++c)
#pragma unroll
    for (int tt = 0; tt < 4; ++tt)
#pragma unroll
      for (int r = 0; r < 4; ++r) sc[c][tt][r] *= inv[r];

  // ---- pass 2: PV ----
  f32x4 o[4];
#pragma unroll
  for (int dt = 0; dt < 4; ++dt) o[dt] = (f32x4){0.f, 0.f, 0.f, 0.f};

  {
    i32x4 vr[2];
#pragma unroll
    for (int i = 0; i < 2; ++i) {
      int rr = srow + i * 32;
      int js = jlo + jel; js = js < 0 ? 0 : (js > 2040 ? 2040 : js);
      vr[i] = *(const i32x4*)(vgbase + 2 * ((size_t)rr * 2048 + js));
    }
    __syncthreads();   // pass1 readers done before reusing LDS phase boundary
#pragma unroll
    for (int i = 0; i < 2; ++i) {
      int rr = srow + i * 32;
      *(i32x4*)(Vs[0] + rr * 128 + (soff ^ ((rr & 7) << 4))) = vr[i];
    }
  }
  __syncthreads();

  char* pw = Ps[wave];
#pragma unroll
  for (int c = 0; c < 5; ++c) {
    int cur = c & 1;
    i32x4 nv[2];
    if (c < 4) {
#pragma unroll
      for (int i = 0; i < 2; ++i) {
        int rr = srow + i * 32;
        int js = jlo + (c + 1) * 64 + jel; js = js < 0 ? 0 : (js > 2040 ? 2040 : js);
        nv[i] = *(const i32x4*)(vgbase + 2 * ((size_t)rr * 2048 + js));
      }
    }
    // write P chunk (per-wave LDS, same-wave RAW handled by lgkmcnt)
#pragma unroll
    for (int tt = 0; tt < 4; ++tt)
#pragma unroll
      for (int r = 0; r < 4; ++r)
        *(unsigned short*)(pw + (4 * lg + r) * 144 + (tt * 16 + l15) * 2) = f2bf(sc[c][tt][r]);
    short8 pa0 = *(const short8*)(pw + l15 * 144 + lg * 16);
    short8 pa1 = *(const short8*)(pw + l15 * 144 + 64 + lg * 16);
#pragma unroll
    for (int dt = 0; dt < 4; ++dt) {
      int row = dt * 16 + l15;
      short8 v0 = *(const short8*)(Vs[cur] + row * 128 + ((lg * 16) ^ ((row & 7) << 4)));
      short8 v1 = *(const short8*)(Vs[cur] + row * 128 + ((64 + lg * 16) ^ ((row & 7) << 4)));
      o[dt] = __builtin_amdgcn_mfma_f32_16x16x32_bf16(pa0, v0, o[dt], 0, 0, 0);
      o[dt] = __builtin_amdgcn_mfma_f32_16x16x32_bf16(pa1, v1, o[dt], 0, 0, 0);
    }
    if (c < 4) {
      __syncthreads();
#pragma unroll
      for (int i = 0; i < 2; ++i) {
        int rr = srow + i * 32;
        *(i32x4*)(Vs[cur ^ 1] + rr * 128 + (soff ^ ((rr & 7) << 4))) = nv[i];
      }
      __syncthreads();
    }
  }

  // epilogue
  char* ob = (char*)out + 2 * ((size_t)(b * L_SEQ + q0 + wave * 16) * D_MODEL + h * 64);
#pragma unroll
  for (int dt = 0; dt < 4; ++dt)
#pragma unroll
    for (int r = 0; r < 4; ++r)
      *(unsigned short*)(ob + 2 * ((size_t)(4 * lg + r) * D_MODEL + dt * 16 + l15)) = f2bf(o[dt][r]);
}

// ---------------- launcher ----------------
extern "C" void kernel_launch(void* const* d_in, const int* in_sizes, int n_in,
                              void* d_out, int out_size, void* d_ws, size_t ws_size,
                              hipStream_t stream) {
  const float* x      = (const float*)d_in[0];
  const float* qkv_w  = (const float*)d_in[1];
  const float* qkv_b  = (const float*)d_in[2];
  const float* out_w  = (const float*)d_in[3];
  const float* out_b  = (const float*)d_in[4];
  const float* ln1_g  = (const float*)d_in[5];
  const float* ln1_b  = (const float*)d_in[6];
  const float* ln2_g  = (const float*)d_in[7];
  const float* ln2_b  = (const float*)d_in[8];
  const float* ffn_w1 = (const float*)d_in[9];
  const float* ffn_b1 = (const float*)d_in[10];
  const float* ffn_w2 = (const float*)d_in[11];
  const float* ffn_b2 = (const float*)d_in[12];
  float* out = (float*)d_out;
  (void)in_sizes; (void)n_in; (void)out_size; (void)ws_size;

  char* ws = (char*)d_ws;
  size_t off = 0;
  auto alloc = [&](size_t bytes) {
    char* p = ws + off;
    off += (bytes + 255) & ~(size_t)255;
    return p;
  };
  __hip_bfloat16* hbuf    = (__hip_bfloat16*)alloc((size_t)NROWS * 1024 * 2);
  __hip_bfloat16* qkvbuf  = (__hip_bfloat16*)alloc((size_t)NROWS * 3072 * 2);
  __hip_bfloat16* attnbuf = (__hip_bfloat16*)alloc((size_t)NROWS * 1024 * 2);
  float*          x2buf   = (float*)alloc((size_t)NROWS * 1024 * 4);
  __hip_bfloat16* wqkvT   = (__hip_bfloat16*)alloc((size_t)3072 * 1024 * 2);
  __hip_bfloat16* woutT   = (__hip_bfloat16*)alloc((size_t)1024 * 1024 * 2);
  __hip_bfloat16* wf1T    = (__hip_bfloat16*)alloc((size_t)2048 * 1024 * 2);
  __hip_bfloat16* wf2T    = (__hip_bfloat16*)alloc((size_t)1024 * 2048 * 2);
  __hip_bfloat16* vTbuf   = (__hip_bfloat16*)alloc((size_t)32 * 64 * 2048 * 2);
  __hip_bfloat16* gbuf    = qkvbuf;   // reuse: qkv dead after attention

  dim3 blk(256);
  wtrans_kernel<<<dim3(3072 / 32, 1024 / 32), blk, 0, stream>>>(qkv_w, wqkvT, 1024, 3072);
  wtrans_kernel<<<dim3(1024 / 32, 1024 / 32), blk, 0, stream>>>(out_w, woutT, 1024, 1024);
  wtrans_kernel<<<dim3(2048 / 32, 1024 / 32), blk, 0, stream>>>(ffn_w1, wf1T, 1024, 2048);
  wtrans_kernel<<<dim3(1024 / 32, 2048 / 32), blk, 0, stream>>>(ffn_w2, wf2T, 2048, 1024);

  ln_kernel<<<NROWS, blk, 0, stream>>>(x, ln1_g, ln1_b, hbuf);
  gemm_kernel<0><<<dim3(3072 / 128, NROWS / 128), blk, 0, stream>>>(hbuf, wqkvT, qkv_b, nullptr, qkvbuf, NROWS, 3072, 1024);
  vtrans_kernel<<<dim3(L_SEQ / 64, BATCH * N_HEADS), blk, 0, stream>>>(qkvbuf, vTbuf);
  attn_mfma_kernel<<<dim3(L_SEQ / 64, BATCH * N_HEADS), blk, 0, stream>>>(qkvbuf, vTbuf, attnbuf);
  gemm_kernel<2><<<dim3(1024 / 128, NROWS / 128), blk, 0, stream>>>(attnbuf, woutT, out_b, x, x2buf, NROWS, 1024, 1024);
  ln_kernel<<<NROWS, blk, 0, stream>>>(x2buf, ln2_g, ln2_b, hbuf);
  gemm_kernel<1><<<dim3(2048 / 128, NROWS / 128), blk, 0, stream>>>(hbuf, wf1T, ffn_b1, nullptr, gbuf, NROWS, 2048, 1024);
  gemm_kernel<2><<<dim3(1024 / 128, NROWS / 128), blk, 0, stream>>>(gbuf, wf2T, ffn_b2, x2buf, out, NROWS, 1024, 2048);
}